// Round 13
// baseline (429.013 us; speedup 1.0000x reference)
//
#include <hip/hip_runtime.h>

#define NV    12288
#define CIN   128
#define COUT  128
#define DEG   9
#define NB    8
#define NROWS (NB * NV)        // 98304
#define KTOT  512              // 4 segments * 128
#define BM    384              // rows per block; 256 blocks = 1/CU exactly
#define NBLK_SP 1024           // spmm3_fused grid: 4 blocks/CU (capacity 8)

typedef unsigned short bfu;
typedef __attribute__((ext_vector_type(8))) short short8;
typedef __attribute__((ext_vector_type(4))) float floatx4;

__device__ __forceinline__ float bf2f(unsigned short u) {
    union { unsigned int i; float f; } x;
    x.i = ((unsigned int)u) << 16;
    return x.f;
}
__device__ __forceinline__ unsigned short f2bf(float f) {
    union { float f; unsigned int i; } x;
    x.f = f;
    unsigned int r = x.i + 0x7FFFu + ((x.i >> 16) & 1u);   // round-nearest-even
    return (unsigned short)(r >> 16);
}
__device__ __forceinline__ void gload16(const void* g, void* l) {
    __builtin_amdgcn_global_load_lds(
        (const __attribute__((address_space(1))) unsigned int*)g,
        (__attribute__((address_space(3))) unsigned int*)l, 16, 0, 0);
}

// ---------------------------------------------------------------------------
// Fused prep (round-7 proven):
//   blocks [0, 6144)      : x fp32 -> xb bf16, 8 elems/thread
//   blocks [6144, 6400)   : W[(c*4+s)*128+o] fp32 -> Wt[o*512+s*128+c] bf16
//   block  6400           : zero stats[0..255] + barrier counters [256],[257]
// ---------------------------------------------------------------------------
__global__ __launch_bounds__(256)
void prep_kernel(const float* __restrict__ x, bfu* __restrict__ xb,
                 const float* __restrict__ W, bfu* __restrict__ Wt,
                 float* __restrict__ stats)
{
    const int blk = blockIdx.x;
    const int t   = threadIdx.x;
    if (blk < 6144) {
        const size_t i = ((size_t)blk * 256 + t) * 8;
        const float4 a = *reinterpret_cast<const float4*>(x + i);
        const float4 b = *reinterpret_cast<const float4*>(x + i + 4);
        short8 r;
        r[0] = (short)f2bf(a.x); r[1] = (short)f2bf(a.y);
        r[2] = (short)f2bf(a.z); r[3] = (short)f2bf(a.w);
        r[4] = (short)f2bf(b.x); r[5] = (short)f2bf(b.y);
        r[6] = (short)f2bf(b.z); r[7] = (short)f2bf(b.w);
        *reinterpret_cast<short8*>(xb + i) = r;
    } else if (blk < 6400) {
        const int i = (blk - 6144) * 256 + t;      // [0, 65536)
        const int o = i >> 9;
        const int kap = i & 511;
        const int s = kap >> 7;
        const int c = kap & 127;
        Wt[i] = f2bf(W[(size_t)(c * 4 + s) * COUT + o]);
    } else {
        stats[t] = 0.f;                            // sum | sumsq
        if (t < 2) stats[2 * COUT + t] = 0.f;      // gemm ctr | spmm ctr
    }
}

// ---------------------------------------------------------------------------
// One SpMM tile (16 vertices), round-6 proven body.
//   out[b,v,c] = sum_e vals[v,e]*src[b,cols[v,e],c]          (sub==null)
//   out[b,v,c] = 2*sum - sub[b,v,c]                          (sub!=null)
// ---------------------------------------------------------------------------
__device__ __forceinline__
void spmm_tile(const bfu* __restrict__ src, const bfu* __restrict__ sub,
               bfu* __restrict__ outp, const int* __restrict__ cols,
               const float* __restrict__ vals, int b, int vtile, int t)
{
    const int v  = vtile * 16 + (t >> 4);
    const int c0 = (t & 15) * 8;

    int   ec[DEG];
    float ev[DEG];
#pragma unroll
    for (int e = 0; e < DEG; ++e) {            // 16 lanes share v -> L1 broadcast
        ec[e] = cols[v * DEG + e];
        ev[e] = vals[v * DEG + e];
    }

    float acc[8];
#pragma unroll
    for (int j = 0; j < 8; ++j) acc[j] = 0.f;

    const size_t bbase = (size_t)b * NV * CIN;
#pragma unroll
    for (int e = 0; e < DEG; ++e) {
        const short8 s = *reinterpret_cast<const short8*>(
            src + bbase + (size_t)ec[e] * CIN + c0);
#pragma unroll
        for (int j = 0; j < 8; ++j)
            acc[j] = fmaf(ev[e], bf2f((unsigned short)s[j]), acc[j]);
    }

    if (sub != nullptr) {
        const short8 s0 = *reinterpret_cast<const short8*>(
            sub + bbase + (size_t)v * CIN + c0);
#pragma unroll
        for (int j = 0; j < 8; ++j)
            acc[j] = 2.f * acc[j] - bf2f((unsigned short)s0[j]);
    }

    short8 r;
#pragma unroll
    for (int j = 0; j < 8; ++j) r[j] = (short)f2bf(acc[j]);
    *reinterpret_cast<short8*>(outp + bbase + (size_t)v * CIN + c0) = r;
}

// ---------------------------------------------------------------------------
// Monotone software grid barrier (release-add / acquire-spin, agent scope:
// emits the L2 wb/inv pair -> data visibility does NOT depend on block->XCD
// mapping; the batch partition remains a perf-only heuristic).
// ---------------------------------------------------------------------------
__device__ __forceinline__ void gridbar(unsigned int* ctr, unsigned int target)
{
    __syncthreads();                              // all waves' stores in L2
    if (threadIdx.x == 0) {
        __hip_atomic_fetch_add(ctr, 1u, __ATOMIC_RELEASE,
                               __HIP_MEMORY_SCOPE_AGENT);
        while (__hip_atomic_load(ctr, __ATOMIC_ACQUIRE,
                                 __HIP_MEMORY_SCOPE_AGENT) < target) { }
    }
    __syncthreads();
}

// ---------------------------------------------------------------------------
// All three Chebyshev SpMMs in one kernel, two internal grid barriers.
// 1024 blocks x 256 thr; __launch_bounds__(256,4) caps VGPR at 128 ->
// 4 blocks/CU guaranteed resident (capacity 8, 2x margin; no LDS).
// Block = (b = blk&7 [batch->XCD partition], tile-group = blk>>3 of 6 tiles).
// Phases independent per-tile -> cross-tile ILP within a phase.
// ---------------------------------------------------------------------------
__global__ __launch_bounds__(256, 4)
void spmm3_fused(const bfu* __restrict__ xb, bfu* __restrict__ t1,
                 bfu* __restrict__ t2, bfu* __restrict__ t3,
                 const int* __restrict__ cols, const float* __restrict__ vals,
                 float* __restrict__ stats)
{
    unsigned int* ctr = (unsigned int*)&stats[2 * COUT + 1];
    const int t  = threadIdx.x;
    const int b  = blockIdx.x & 7;
    const int tg = (int)(blockIdx.x >> 3);        // 0..127, 6 tiles each

    for (int i = 0; i < 6; ++i)                   // T1 = L x
        spmm_tile(xb, nullptr, t1, cols, vals, b, tg * 6 + i, t);
    gridbar(ctr, 1 * NBLK_SP);

    for (int i = 0; i < 6; ++i)                   // T2 = 2 L T1 - x
        spmm_tile(t1, xb, t2, cols, vals, b, tg * 6 + i, t);
    gridbar(ctr, 2 * NBLK_SP);

    for (int i = 0; i < 6; ++i)                   // T3 = 2 L T2 - T1
        spmm_tile(t2, t1, t3, cols, vals, b, tg * 6 + i, t);
}

// ---------------------------------------------------------------------------
// MFMA GEMM + fused BN via software grid barrier (round-12 proven).
// BM=384, 1 block/CU (96 KB LDS), 512 thr (8 waves, 4m x 2n), BK=32,
// 3-stage counted-vmcnt pipeline. __launch_bounds__(512,2): 256-VGPR cap.
// ---------------------------------------------------------------------------
__global__ __launch_bounds__(512, 2)
void gemm_mfma(const bfu* __restrict__ A0, const bfu* __restrict__ A1,
               const bfu* __restrict__ A2, const bfu* __restrict__ A3,
               const bfu* __restrict__ Wt, float* __restrict__ gstats,
               const float* __restrict__ gamma, const float* __restrict__ beta,
               float* __restrict__ outp)
{
    extern __shared__ char smem[];                // 98304 B

    const int t    = threadIdx.x;
    const int lane = t & 63;
    const int wid  = t >> 6;                      // 0..7
    const int wr   = wid >> 1;                    // 0..3 row-wave
    const int wc   = wid & 1;                     // 0..1 col-wave
    const int rbase = blockIdx.x * BM;

    floatx4 acc[6][4];
#pragma unroll
    for (int m = 0; m < 6; ++m)
#pragma unroll
        for (int n = 0; n < 4; ++n) acc[m][n] = (floatx4){0.f, 0.f, 0.f, 0.f};

    const bfu* segs[4] = {A0, A1, A2, A3};

#define STAGE(KT, BUF)                                                        \
    {                                                                         \
        const bfu* As_ = segs[(KT) >> 2];                                     \
        const int  cb_ = ((KT) & 3) * 32;                                     \
        _Pragma("unroll")                                                     \
        for (int p = 0; p < 3; ++p) {                                         \
            const int flat = p * 512 + t;                                     \
            const int rr   = flat >> 2;                                       \
            const int ck   = flat & 3;                                        \
            gload16(As_ + (size_t)(rbase + rr) * CIN + cb_                    \
                        + ((ck ^ ((rr >> 1) & 3)) << 3),                      \
                    smem + (BUF) * 24576 + flat * 16);                        \
        }                                                                     \
        {                                                                     \
            const int nn = t >> 2;                                            \
            const int ck = t & 3;                                             \
            gload16(Wt + (size_t)nn * KTOT + (KT) * 32                        \
                       + ((ck ^ ((nn >> 1) & 3)) << 3),                       \
                    smem + 73728 + (BUF) * 8192 + t * 16);                    \
        }                                                                     \
    }

    STAGE(0, 0);
    STAGE(1, 1);
    asm volatile("s_waitcnt vmcnt(4)\n\ts_barrier" ::: "memory");  // tile 0 ready

    const int rsw   = ((lane & 15) >> 1) & 3;     // row-swizzle bits
    const int chunk = ((lane >> 4) ^ rsw) * 16;   // byte offset of wanted k-chunk

#pragma unroll
    for (int kt = 0; kt < 16; ++kt) {
        if (kt + 2 < 16) STAGE(kt + 2, (kt + 2) % 3);   // 2-deep prefetch

        const char* abase = smem + (kt % 3) * 24576;
        const char* bbase = smem + 73728 + (kt % 3) * 8192;
        short8 a[6], b[4];
#pragma unroll
        for (int m = 0; m < 6; ++m)
            a[m] = *reinterpret_cast<const short8*>(
                abase + (wr * 96 + m * 16 + (lane & 15)) * 64 + chunk);
#pragma unroll
        for (int n = 0; n < 4; ++n)
            b[n] = *reinterpret_cast<const short8*>(
                bbase + (wc * 64 + n * 16 + (lane & 15)) * 64 + chunk);
#pragma unroll
        for (int m = 0; m < 6; ++m)
#pragma unroll
            for (int n = 0; n < 4; ++n)
                acc[m][n] = __builtin_amdgcn_mfma_f32_16x16x32_bf16(
                    a[m], b[n], acc[m][n], 0, 0, 0);

        if (kt <= 13)
            asm volatile("s_waitcnt vmcnt(4)\n\ts_barrier" ::: "memory");
        else if (kt == 14)
            asm volatile("s_waitcnt vmcnt(0)\n\ts_barrier" ::: "memory");
    }
#undef STAGE

    __syncthreads();                              // done with LDS tiles
    float* sred = (float*)smem;                   // alias buffer A0
    float* qred = sred + COUT;
    if (t < COUT) { sred[t] = 0.f; qred[t] = 0.f; }
    __syncthreads();

    const int batch = rbase / NV;                 // 384 | 12288 -> no straddle
    const int v0 = (rbase % NV) + wr * 96 + (lane >> 4) * 4;
    const int ob = wc * 64 + (lane & 15);

    // block-local BN partial stats -> gstats atomics
#pragma unroll
    for (int n = 0; n < 4; ++n) {
        const int o = ob + n * 16;
        float s = 0.f, q = 0.f;
#pragma unroll
        for (int m = 0; m < 6; ++m) {
            const floatx4 v4 = acc[m][n];
#pragma unroll
            for (int j = 0; j < 4; ++j) {
                s += v4[j];
                q = fmaf(v4[j], v4[j], q);
            }
        }
        s += __shfl_xor(s, 16); s += __shfl_xor(s, 32);
        q += __shfl_xor(q, 16); q += __shfl_xor(q, 32);
        if ((lane >> 4) == 0) {
            atomicAdd(&sred[o], s);
            atomicAdd(&qred[o], q);
        }
    }
    __syncthreads();
    if (t < COUT) {
        atomicAdd(&gstats[t], sred[t]);
        atomicAdd(&gstats[COUT + t], qred[t]);
    }
    __syncthreads();                              // drains the atomics

    // ---- software grid barrier (256 blocks, all co-resident: 1/CU) ----
    unsigned int* ctr = (unsigned int*)&gstats[2 * COUT];
    if (t == 0) {
        __threadfence();                          // publish this block's atomics
        atomicAdd(ctr, 1u);
        while (__hip_atomic_load(ctr, __ATOMIC_ACQUIRE,
                                 __HIP_MEMORY_SCOPE_AGENT) < gridDim.x) { }
        __threadfence();                          // acquire completed gstats
    }
    __syncthreads();

    // normalize own accumulators, write fp32 out[b,o,v]
    const float invN = 1.0f / (float)NROWS;
#pragma unroll
    for (int n = 0; n < 4; ++n) {
        const int o = ob + n * 16;
        const float mean = gstats[o] * invN;
        const float var  = gstats[COUT + o] * invN - mean * mean;
        const float sc   = rsqrtf(var + 1e-5f) * gamma[o];
        const float sh   = beta[o] - mean * sc;
        float* obase = outp + ((size_t)batch * COUT + o) * NV + v0;
#pragma unroll
        for (int m = 0; m < 6; ++m) {
            const floatx4 v4 = acc[m][n];
            float4 r;
            r.x = fmaf(v4[0], sc, sh);
            r.y = fmaf(v4[1], sc, sh);
            r.z = fmaf(v4[2], sc, sh);
            r.w = fmaf(v4[3], sc, sh);
            *reinterpret_cast<float4*>(obase + m * 16) = r;
        }
    }
}

// ---------------------------------------------------------------------------
extern "C" void kernel_launch(void* const* d_in, const int* in_sizes, int n_in,
                              void* d_out, int out_size, void* d_ws, size_t ws_size,
                              hipStream_t stream)
{
    (void)in_sizes; (void)n_in; (void)out_size; (void)ws_size;

    const float* x     = (const float*)d_in[0];
    const int*   cols  = (const int*)  d_in[2];
    const float* vals  = (const float*)d_in[3];
    const float* W     = (const float*)d_in[4];
    const float* gamma = (const float*)d_in[5];
    const float* beta  = (const float*)d_in[6];
    float*       out   = (float*)d_out;

    const size_t bufE = (size_t)NB * NV * CIN;      // 12,582,912 elems

    bfu* xb    = (bfu*)d_ws;
    bfu* t1    = xb + bufE;
    bfu* t2    = t1 + bufE;
    bfu* t3    = t2 + bufE;
    bfu* Wt    = t3 + bufE;                         // 65536 bf16
    float* stats = (float*)(Wt + 65536);            // 258 floats

    const dim3 blk(256);

    prep_kernel <<<6401, blk, 0, stream>>>(x, xb, W, Wt, stats);

    spmm3_fused <<<NBLK_SP, blk, 0, stream>>>(xb, t1, t2, t3, cols, vals, stats);

    gemm_mfma <<<NROWS / BM, dim3(512), 98304, stream>>>(
        xb, t1, t2, t3, Wt, stats, gamma, beta, out);
}

// Round 14
// 112.866 us; speedup vs baseline: 3.8011x; 3.8011x over previous
//
#include <hip/hip_runtime.h>

#define NV    12288
#define CIN   128
#define COUT  128
#define DEG   9
#define NB    8
#define NROWS (NB * NV)        // 98304
#define KTOT  512              // 4 segments * 128
#define BM    384              // rows per block; 256 blocks = 1/CU exactly

typedef unsigned short bfu;
typedef __attribute__((ext_vector_type(8))) short short8;
typedef __attribute__((ext_vector_type(4))) float floatx4;

__device__ __forceinline__ float bf2f(unsigned short u) {
    union { unsigned int i; float f; } x;
    x.i = ((unsigned int)u) << 16;
    return x.f;
}
__device__ __forceinline__ unsigned short f2bf(float f) {
    union { float f; unsigned int i; } x;
    x.f = f;
    unsigned int r = x.i + 0x7FFFu + ((x.i >> 16) & 1u);   // round-nearest-even
    return (unsigned short)(r >> 16);
}
__device__ __forceinline__ void gload16(const void* g, void* l) {
    __builtin_amdgcn_global_load_lds(
        (const __attribute__((address_space(1))) unsigned int*)g,
        (__attribute__((address_space(3))) unsigned int*)l, 16, 0, 0);
}

// ---------------------------------------------------------------------------
// Fused prep (round-7 proven):
//   blocks [0, 6144)      : x fp32 -> xb bf16, 8 elems/thread
//   blocks [6144, 6400)   : W[(c*4+s)*128+o] fp32 -> Wt[o*512+s*128+c] bf16
//   block  6400           : zero stats[0..255] + barrier counter stats[256]
// ---------------------------------------------------------------------------
__global__ __launch_bounds__(256)
void prep_kernel(const float* __restrict__ x, bfu* __restrict__ xb,
                 const float* __restrict__ W, bfu* __restrict__ Wt,
                 float* __restrict__ stats)
{
    const int blk = blockIdx.x;
    const int t   = threadIdx.x;
    if (blk < 6144) {
        const size_t i = ((size_t)blk * 256 + t) * 8;
        const float4 a = *reinterpret_cast<const float4*>(x + i);
        const float4 b = *reinterpret_cast<const float4*>(x + i + 4);
        short8 r;
        r[0] = (short)f2bf(a.x); r[1] = (short)f2bf(a.y);
        r[2] = (short)f2bf(a.z); r[3] = (short)f2bf(a.w);
        r[4] = (short)f2bf(b.x); r[5] = (short)f2bf(b.y);
        r[6] = (short)f2bf(b.z); r[7] = (short)f2bf(b.w);
        *reinterpret_cast<short8*>(xb + i) = r;
    } else if (blk < 6400) {
        const int i = (blk - 6144) * 256 + t;      // [0, 65536)
        const int o = i >> 9;
        const int kap = i & 511;
        const int s = kap >> 7;
        const int c = kap & 127;
        Wt[i] = f2bf(W[(size_t)(c * 4 + s) * COUT + o]);
    } else {
        stats[t] = 0.f;                            // sum | sumsq
        if (t == 0) stats[2 * COUT] = 0.f;         // spin-barrier counter
    }
}

// ---------------------------------------------------------------------------
// SpMM in bf16 storage, fp32 math — XCD/batch-partitioned, 2 vertices per
// thread for 18 outstanding gathers (latency-bound fix; round-6 body x2).
//   out[b,v,c] = sum_e vals[v,e]*src[b,cols[v,e],c]          (sub==null)
//   out[b,v,c] = 2*sum - sub[b,v,c]                          (sub!=null)
// Block = 32 vertices x one batch; b = blk&7 (batch->XCD partition).
// ---------------------------------------------------------------------------
__global__ __launch_bounds__(256)
void spmm_bf16(const bfu* __restrict__ src, const bfu* __restrict__ sub,
               bfu* __restrict__ outp, const int* __restrict__ cols,
               const float* __restrict__ vals)
{
    const int t  = threadIdx.x;
    const int b  = blockIdx.x & 7;
    const int vt = blockIdx.x >> 3;            // 0..383
    const int v0 = vt * 32 + (t >> 4);
    const int v1 = v0 + 16;
    const int c0 = (t & 15) * 8;

    int   ec0[DEG], ec1[DEG];
    float ev0[DEG], ev1[DEG];
#pragma unroll
    for (int e = 0; e < DEG; ++e) {            // 16 lanes share v -> L1 broadcast
        ec0[e] = cols[v0 * DEG + e];
        ev0[e] = vals[v0 * DEG + e];
        ec1[e] = cols[v1 * DEG + e];
        ev1[e] = vals[v1 * DEG + e];
    }

    float a0[8], a1[8];
#pragma unroll
    for (int j = 0; j < 8; ++j) { a0[j] = 0.f; a1[j] = 0.f; }

    const size_t bbase = (size_t)b * NV * CIN;
#pragma unroll
    for (int e = 0; e < DEG; ++e) {
        const short8 s0 = *reinterpret_cast<const short8*>(
            src + bbase + (size_t)ec0[e] * CIN + c0);
        const short8 s1 = *reinterpret_cast<const short8*>(
            src + bbase + (size_t)ec1[e] * CIN + c0);
#pragma unroll
        for (int j = 0; j < 8; ++j) {
            a0[j] = fmaf(ev0[e], bf2f((unsigned short)s0[j]), a0[j]);
            a1[j] = fmaf(ev1[e], bf2f((unsigned short)s1[j]), a1[j]);
        }
    }

    if (sub != nullptr) {
        const short8 u0 = *reinterpret_cast<const short8*>(
            sub + bbase + (size_t)v0 * CIN + c0);
        const short8 u1 = *reinterpret_cast<const short8*>(
            sub + bbase + (size_t)v1 * CIN + c0);
#pragma unroll
        for (int j = 0; j < 8; ++j) {
            a0[j] = 2.f * a0[j] - bf2f((unsigned short)u0[j]);
            a1[j] = 2.f * a1[j] - bf2f((unsigned short)u1[j]);
        }
    }

    short8 r0, r1;
#pragma unroll
    for (int j = 0; j < 8; ++j) {
        r0[j] = (short)f2bf(a0[j]);
        r1[j] = (short)f2bf(a1[j]);
    }
    *reinterpret_cast<short8*>(outp + bbase + (size_t)v0 * CIN + c0) = r0;
    *reinterpret_cast<short8*>(outp + bbase + (size_t)v1 * CIN + c0) = r1;
}

// ---------------------------------------------------------------------------
// MFMA GEMM + fused BN via software grid barrier (round-12 proven, exact).
// BM=384, 1 block/CU (96 KB LDS), 512 thr (8 waves, 4m x 2n), BK=32,
// 3-stage counted-vmcnt pipeline. __launch_bounds__(512,2): 256-VGPR cap.
// Spin uses RELAXED loads + one threadfence outside (NEVER acquire inside
// the spin — agent-scope acquire invalidates the XCD L2 every iteration;
// round-13 lesson: that cost 8x on the co-running memory traffic).
// ---------------------------------------------------------------------------
__global__ __launch_bounds__(512, 2)
void gemm_mfma(const bfu* __restrict__ A0, const bfu* __restrict__ A1,
               const bfu* __restrict__ A2, const bfu* __restrict__ A3,
               const bfu* __restrict__ Wt, float* __restrict__ gstats,
               const float* __restrict__ gamma, const float* __restrict__ beta,
               float* __restrict__ outp)
{
    extern __shared__ char smem[];                // 98304 B

    const int t    = threadIdx.x;
    const int lane = t & 63;
    const int wid  = t >> 6;                      // 0..7
    const int wr   = wid >> 1;                    // 0..3 row-wave
    const int wc   = wid & 1;                     // 0..1 col-wave
    const int rbase = blockIdx.x * BM;

    floatx4 acc[6][4];
#pragma unroll
    for (int m = 0; m < 6; ++m)
#pragma unroll
        for (int n = 0; n < 4; ++n) acc[m][n] = (floatx4){0.f, 0.f, 0.f, 0.f};

    const bfu* segs[4] = {A0, A1, A2, A3};

#define STAGE(KT, BUF)                                                        \
    {                                                                         \
        const bfu* As_ = segs[(KT) >> 2];                                     \
        const int  cb_ = ((KT) & 3) * 32;                                     \
        _Pragma("unroll")                                                     \
        for (int p = 0; p < 3; ++p) {                                         \
            const int flat = p * 512 + t;                                     \
            const int rr   = flat >> 2;                                       \
            const int ck   = flat & 3;                                        \
            gload16(As_ + (size_t)(rbase + rr) * CIN + cb_                    \
                        + ((ck ^ ((rr >> 1) & 3)) << 3),                      \
                    smem + (BUF) * 24576 + flat * 16);                        \
        }                                                                     \
        {                                                                     \
            const int nn = t >> 2;                                            \
            const int ck = t & 3;                                             \
            gload16(Wt + (size_t)nn * KTOT + (KT) * 32                        \
                       + ((ck ^ ((nn >> 1) & 3)) << 3),                       \
                    smem + 73728 + (BUF) * 8192 + t * 16);                    \
        }                                                                     \
    }

    STAGE(0, 0);
    STAGE(1, 1);
    asm volatile("s_waitcnt vmcnt(4)\n\ts_barrier" ::: "memory");  // tile 0 ready

    const int rsw   = ((lane & 15) >> 1) & 3;     // row-swizzle bits
    const int chunk = ((lane >> 4) ^ rsw) * 16;   // byte offset of wanted k-chunk

#pragma unroll
    for (int kt = 0; kt < 16; ++kt) {
        if (kt + 2 < 16) STAGE(kt + 2, (kt + 2) % 3);   // 2-deep prefetch

        const char* abase = smem + (kt % 3) * 24576;
        const char* bbase = smem + 73728 + (kt % 3) * 8192;
        short8 a[6], b[4];
#pragma unroll
        for (int m = 0; m < 6; ++m)
            a[m] = *reinterpret_cast<const short8*>(
                abase + (wr * 96 + m * 16 + (lane & 15)) * 64 + chunk);
#pragma unroll
        for (int n = 0; n < 4; ++n)
            b[n] = *reinterpret_cast<const short8*>(
                bbase + (wc * 64 + n * 16 + (lane & 15)) * 64 + chunk);
#pragma unroll
        for (int m = 0; m < 6; ++m)
#pragma unroll
            for (int n = 0; n < 4; ++n)
                acc[m][n] = __builtin_amdgcn_mfma_f32_16x16x32_bf16(
                    a[m], b[n], acc[m][n], 0, 0, 0);

        if (kt <= 13)
            asm volatile("s_waitcnt vmcnt(4)\n\ts_barrier" ::: "memory");
        else if (kt == 14)
            asm volatile("s_waitcnt vmcnt(0)\n\ts_barrier" ::: "memory");
    }
#undef STAGE

    __syncthreads();                              // done with LDS tiles
    float* sred = (float*)smem;                   // alias buffer A0
    float* qred = sred + COUT;
    if (t < COUT) { sred[t] = 0.f; qred[t] = 0.f; }
    __syncthreads();

    const int batch = rbase / NV;                 // 384 | 12288 -> no straddle
    const int v0 = (rbase % NV) + wr * 96 + (lane >> 4) * 4;
    const int ob = wc * 64 + (lane & 15);

    // block-local BN partial stats -> gstats atomics
#pragma unroll
    for (int n = 0; n < 4; ++n) {
        const int o = ob + n * 16;
        float s = 0.f, q = 0.f;
#pragma unroll
        for (int m = 0; m < 6; ++m) {
            const floatx4 v4 = acc[m][n];
#pragma unroll
            for (int j = 0; j < 4; ++j) {
                s += v4[j];
                q = fmaf(v4[j], v4[j], q);
            }
        }
        s += __shfl_xor(s, 16); s += __shfl_xor(s, 32);
        q += __shfl_xor(q, 16); q += __shfl_xor(q, 32);
        if ((lane >> 4) == 0) {
            atomicAdd(&sred[o], s);
            atomicAdd(&qred[o], q);
        }
    }
    __syncthreads();
    if (t < COUT) {
        atomicAdd(&gstats[t], sred[t]);
        atomicAdd(&gstats[COUT + t], qred[t]);
    }
    __syncthreads();                              // drains the atomics

    // ---- software grid barrier (256 blocks, all co-resident: 1/CU) ----
    unsigned int* ctr = (unsigned int*)&gstats[2 * COUT];
    if (t == 0) {
        __threadfence();                          // publish this block's atomics
        atomicAdd(ctr, 1u);
        while (__hip_atomic_load(ctr, __ATOMIC_RELAXED,
                                 __HIP_MEMORY_SCOPE_AGENT) < gridDim.x) { }
        __threadfence();                          // acquire completed gstats
    }
    __syncthreads();

    // normalize own accumulators, write fp32 out[b,o,v]
    const float invN = 1.0f / (float)NROWS;
#pragma unroll
    for (int n = 0; n < 4; ++n) {
        const int o = ob + n * 16;
        const float mean = gstats[o] * invN;
        const float var  = gstats[COUT + o] * invN - mean * mean;
        const float sc   = rsqrtf(var + 1e-5f) * gamma[o];
        const float sh   = beta[o] - mean * sc;
        float* obase = outp + ((size_t)batch * COUT + o) * NV + v0;
#pragma unroll
        for (int m = 0; m < 6; ++m) {
            const floatx4 v4 = acc[m][n];
            float4 r;
            r.x = fmaf(v4[0], sc, sh);
            r.y = fmaf(v4[1], sc, sh);
            r.z = fmaf(v4[2], sc, sh);
            r.w = fmaf(v4[3], sc, sh);
            *reinterpret_cast<float4*>(obase + m * 16) = r;
        }
    }
}

// ---------------------------------------------------------------------------
extern "C" void kernel_launch(void* const* d_in, const int* in_sizes, int n_in,
                              void* d_out, int out_size, void* d_ws, size_t ws_size,
                              hipStream_t stream)
{
    (void)in_sizes; (void)n_in; (void)out_size; (void)ws_size;

    const float* x     = (const float*)d_in[0];
    const int*   cols  = (const int*)  d_in[2];
    const float* vals  = (const float*)d_in[3];
    const float* W     = (const float*)d_in[4];
    const float* gamma = (const float*)d_in[5];
    const float* beta  = (const float*)d_in[6];
    float*       out   = (float*)d_out;

    const size_t bufE = (size_t)NB * NV * CIN;      // 12,582,912 elems

    bfu* xb    = (bfu*)d_ws;
    bfu* t1    = xb + bufE;
    bfu* t2    = t1 + bufE;
    bfu* t3    = t2 + bufE;
    bfu* Wt    = t3 + bufE;                         // 65536 bf16
    float* stats = (float*)(Wt + 65536);            // 257 floats (sum|sumsq|ctr)

    const dim3 blk(256);
    const int spmm_grid = (NV / 32) * NB;           // 3072 blocks

    prep_kernel <<<6401, blk, 0, stream>>>(x, xb, W, Wt, stats);

    spmm_bf16 <<<spmm_grid, blk, 0, stream>>>(xb, nullptr, t1, cols, vals);
    spmm_bf16 <<<spmm_grid, blk, 0, stream>>>(t1, xb,      t2, cols, vals);
    spmm_bf16 <<<spmm_grid, blk, 0, stream>>>(t2, t1,      t3, cols, vals);

    gemm_mfma <<<NROWS / BM, dim3(512), 98304, stream>>>(
        xb, t1, t2, t3, Wt, stats, gamma, beta, out);
}